// Round 5
// baseline (580.529 us; speedup 1.0000x reference)
//
#include <hip/hip_runtime.h>

// LogicGatedSNN: fused 1-row-per-wave, x as in-register bitmask (R5).
//
// R4 post-mortem: kernel ~150us vs ~124-128us floor (805MB @ 6.3 TB/s,
// which IS a mixed read+write ceiling per the D2D copy ubench). VALUBusy
// 8.6%, zero conflicts -> not compute; theory: latency*MLP-bound. Half of
// all load instructions are x4[] loads (L1/L2 hits) that waste vmcnt queue
// slots; in-order vmcnt return means they never complete early anyway.
// R5: x entries are exactly 0.0/1.0 -> pack each lane's 128-element x
// slice into 4 u32 bitmasks ONCE (32 cached loads), then both phases
// reconstruct via cndmask (bit ? c : 0) -- bit-exact, removes 64 of 128
// loads per row -> ~2x per-wave outstanding stream bytes.
// PF 16->8 to cut VGPR (R4's 64-reg tbuf likely capped waves/SIMD at ~5).
// All register arrays compile-time indexed (macros, full unrolls).

#define IN_F 8192
#define OUT_F 8192
#define BLOCK 256
#define ROW4 (IN_F / 4)          // 2048 float4 per row
#define CHUNKS (ROW4 / 64)       // 32 float4 iterations per lane per row
#define PF 8                     // trace-in quads prefetched into registers

typedef float f32x4 __attribute__((ext_vector_type(4)));

// Pack 8 quads (32 x-elements) of this lane's slice into bits [0..31] of XM.
#define PACK_BLOCK(O, XM)                                                 \
    _Pragma("unroll")                                                     \
    for (int k = 0; k < 8; ++k) {                                         \
        const f32x4 xv = x4[((((O) << 3) + k) << 6) + lane];              \
        unsigned b = 0u;                                                  \
        b |= (xv[0] > 0.5f) ? 1u : 0u;                                    \
        b |= (xv[1] > 0.5f) ? 2u : 0u;                                    \
        b |= (xv[2] > 0.5f) ? 4u : 0u;                                    \
        b |= (xv[3] > 0.5f) ? 8u : 0u;                                    \
        (XM) |= b << (k * 4);                                             \
    }

// 8 dot-product quads using syn stream + x bits from XM.
#define DOT_BLOCK(O, XM)                                                  \
    _Pragma("unroll")                                                     \
    for (int k = 0; k < 8; ++k) {                                         \
        const int idx = ((((O) << 3) + k) << 6) + lane;                   \
        const f32x4 s = __builtin_nontemporal_load(&syn4[idx]);           \
        const unsigned bq = (XM) >> (k * 4);                              \
        acc += ((s[0] > 50.0f) && (bq & 1u)) ? 1.0f : 0.0f;               \
        acc += ((s[1] > 50.0f) && (bq & 2u)) ? 1.0f : 0.0f;               \
        acc += ((s[2] > 50.0f) && (bq & 4u)) ? 1.0f : 0.0f;               \
        acc += ((s[3] > 50.0f) && (bq & 8u)) ? 1.0f : 0.0f;               \
    }

// One trace RMW quad: out = clip(t*0.8 + (bit?spike:0), 0, 5). Bit-exact
// vs t*0.8 + spike*xv since xv in {0,1}.
#define TRACE_ONE(T, BQ, DST)                                             \
    {                                                                     \
        const float s0 = ((BQ) & 1u) ? spike : 0.0f;                      \
        const float s1 = ((BQ) & 2u) ? spike : 0.0f;                      \
        const float s2 = ((BQ) & 4u) ? spike : 0.0f;                      \
        const float s3 = ((BQ) & 8u) ? spike : 0.0f;                      \
        f32x4 oo;                                                         \
        oo[0] = fminf(fmaxf((T)[0] * 0.8f + s0, 0.0f), 5.0f);             \
        oo[1] = fminf(fmaxf((T)[1] * 0.8f + s1, 0.0f), 5.0f);             \
        oo[2] = fminf(fmaxf((T)[2] * 0.8f + s2, 0.0f), 5.0f);             \
        oo[3] = fminf(fmaxf((T)[3] * 0.8f + s3, 0.0f), 5.0f);             \
        __builtin_nontemporal_store(oo, (DST));                           \
    }

// 8 streamed trace RMW quads (load + RMW + store).
#define TRACE_BLOCK(O, XM)                                                \
    _Pragma("unroll")                                                     \
    for (int k = 0; k < 8; ++k) {                                         \
        const int idx = ((((O) << 3) + k) << 6) + lane;                   \
        const f32x4 t = __builtin_nontemporal_load(&trR[idx]);            \
        const unsigned bq = (XM) >> (k * 4);                              \
        TRACE_ONE(t, bq, &otrR[idx]);                                     \
    }

__global__ __launch_bounds__(BLOCK) void snn_fused_kernel(
    const f32x4* __restrict__ x4,      // spike_input [IN_F/4]
    const float* __restrict__ syn,     // synapse_states [OUT_F, IN_F]
    const float* __restrict__ mem,     // membrane_potential [OUT_F]
    const float* __restrict__ thr,     // adaptive_threshold [OUT_F]
    const float* __restrict__ refr,    // refractory_period [OUT_F]
    const f32x4* __restrict__ tr4,     // eligibility_trace [OUT_F * IN_F/4]
    float* __restrict__ out_spikes,
    float* __restrict__ out_mem,
    float* __restrict__ out_refr,
    f32x4* __restrict__ otr4)          // out_trace [OUT_F * IN_F/4]
{
    const int wave = threadIdx.x >> 6;           // 0..3
    const int lane = threadIdx.x & 63;
    const int row  = (blockIdx.x << 2) + wave;

    const size_t base4 = (size_t)row * ROW4;
    const f32x4* __restrict__ syn4 = (const f32x4*)syn + base4;
    const f32x4* __restrict__ trR  = tr4  + base4;
    f32x4* __restrict__ otrR       = otr4 + base4;

    // Row scalars (wave-uniform broadcast loads).
    const float r_in = refr[row];
    const float m_in = mem[row];
    const float t_in = thr[row];

    // ---- Prefetch first PF trace-in quads (no spike dependency). ----
    f32x4 tbuf[PF];
    #pragma unroll
    for (int k = 0; k < PF; ++k)
        tbuf[k] = __builtin_nontemporal_load(&trR[(k << 6) + lane]);

    // ---- Pack this lane's x slice (128 elems) into 4 u32 bitmasks. ----
    unsigned xm0 = 0u, xm1 = 0u, xm2 = 0u, xm3 = 0u;
    PACK_BLOCK(0, xm0)
    PACK_BLOCK(1, xm1)
    PACK_BLOCK(2, xm2)
    PACK_BLOCK(3, xm3)

    // ---- Phase 1: current = (syn > 50) . x  (pure syn read stream) ----
    float acc = 0.0f;
    DOT_BLOCK(0, xm0)
    DOT_BLOCK(1, xm1)
    DOT_BLOCK(2, xm2)
    DOT_BLOCK(3, xm3)

    // 64-lane butterfly: every lane ends with the full row sum (exact:
    // operands are 0/1 counts, integer-valued in fp32).
    #pragma unroll
    for (int off = 32; off > 0; off >>= 1)
        acc += __shfl_xor(acc, off, 64);

    // ---- LIF scalars (all lanes compute identically; lane 0 writes) ----
    const float v     = m_in * 0.5f + acc * (1.0f - r_in * 0.5f);
    const float spike = (v >= t_in) ? 1.0f : 0.0f;
    if (lane == 0) {
        out_spikes[row] = spike;
        out_mem[row]    = v * (1.0f - spike);
        out_refr[row]   = fminf(fmaxf(r_in + spike - 0.1f, 0.0f), 1.0f);
    }

    // ---- Phase 2a: consume prefetched quads (zero memory cold-start) ----
    #pragma unroll
    for (int k = 0; k < PF; ++k) {
        const int idx = (k << 6) + lane;
        const unsigned bq = xm0 >> (k * 4);
        TRACE_ONE(tbuf[k], bq, &otrR[idx]);
    }

    // ---- Phase 2b: stream remaining trace RMW (pure 2-stream RMW) ----
    TRACE_BLOCK(1, xm1)
    TRACE_BLOCK(2, xm2)
    TRACE_BLOCK(3, xm3)
}

extern "C" void kernel_launch(void* const* d_in, const int* in_sizes, int n_in,
                              void* d_out, int out_size, void* d_ws, size_t ws_size,
                              hipStream_t stream) {
    const float* x_in  = (const float*)d_in[0];  // spike_input
    const float* syn   = (const float*)d_in[1];  // synapse_states
    const float* mem   = (const float*)d_in[2];  // membrane_potential
    const float* thr   = (const float*)d_in[3];  // adaptive_threshold
    const float* trace = (const float*)d_in[4];  // eligibility_trace
    const float* refr  = (const float*)d_in[5];  // refractory_period

    float* out = (float*)d_out;
    float* out_spikes = out;                                     // [8192]
    float* out_mem    = out + OUT_F;                             // [8192]
    float* out_trace  = out + 2 * OUT_F;                         // [8192^2]
    float* out_refr   = out + 2 * OUT_F + (size_t)OUT_F * IN_F;  // [8192]

    snn_fused_kernel<<<OUT_F / 4, BLOCK, 0, stream>>>(
        (const f32x4*)x_in, syn, mem, thr, refr,
        (const f32x4*)trace,
        out_spikes, out_mem, out_refr,
        (f32x4*)out_trace);
}